// Round 1
// baseline (409.991 us; speedup 1.0000x reference)
//
#include <hip/hip_runtime.h>

// UpsampleUpFIRDn: 2x zero-stuffed upsample + 4x4 FIR (upfirdn2d_up).
// x: [B=8, C=64, H=256, W=256] f32; kernel: [4,4] f32 (already normalized * factor^2).
// Output: [8, 64, 511, 511] f32.
//
// Derivation: out[y,x] = sum_{dy,dx in 0..3} kflip[dy][dx] * padded_dilated[y+dy, x+dx]
// with pad0=2, dilation 2. Input tap exists only when (y+dy-2) and (x+dx-2) are even.
//  -> per output pixel exactly a 2x2 input neighborhood:
//     r0 = (y-1)>>1, r1 = r0+1 ; c0 = (x-1)>>1, c1 = c0+1
//     weights: kernel rows {3,1} (y even) / {2,0} (y odd), cols likewise.
// Only r0/c0 can be -1 (at y=0 / x=0); r1,c1 <= 255 always for OW=2W-1.

__global__ __launch_bounds__(256) void upfirdn_up2_k4(
    const float* __restrict__ x, const float* __restrict__ k,
    float* __restrict__ out, int H, int W, int OH, int OW)
{
    int ox = blockIdx.x * blockDim.x + threadIdx.x;
    if (ox >= OW) return;
    int oy = blockIdx.y;
    int bc = blockIdx.z;

    const float* __restrict__ xp = x + (size_t)bc * H * W;

    int r0 = (oy - 1) >> 1;   // arithmetic shift: -1 at oy==0
    int r1 = r0 + 1;
    int c0 = (ox - 1) >> 1;
    int c1 = c0 + 1;

    int yodd = oy & 1, xodd = ox & 1;
    int i0 = 3 - yodd;  // kernel row for tap r0
    int i1 = 1 - yodd;  // kernel row for tap r1
    int j0 = 3 - xodd;  // kernel col for tap c0
    int j1 = 1 - xodd;  // kernel col for tap c1

    float w00 = k[i0 * 4 + j0];
    float w01 = k[i0 * 4 + j1];
    float w10 = k[i1 * 4 + j0];
    float w11 = k[i1 * 4 + j1];

    bool rok = (r0 >= 0);
    bool cok = (c0 >= 0);

    const float* row0 = xp + (size_t)r0 * W;
    const float* row1 = xp + (size_t)r1 * W;

    float a00 = (rok && cok) ? row0[c0] : 0.0f;
    float a01 = rok ? row0[c1] : 0.0f;
    float a10 = cok ? row1[c0] : 0.0f;
    float a11 = row1[c1];

    float v = w00 * a00 + w01 * a01 + w10 * a10 + w11 * a11;
    out[((size_t)bc * OH + oy) * OW + ox] = v;
}

extern "C" void kernel_launch(void* const* d_in, const int* in_sizes, int n_in,
                              void* d_out, int out_size, void* d_ws, size_t ws_size,
                              hipStream_t stream) {
    const float* x = (const float*)d_in[0];
    const float* k = (const float*)d_in[1];
    float* out = (float*)d_out;

    const int H = 256, W = 256;
    const int OH = 2 * H - 1, OW = 2 * W - 1;  // 511
    int BC = in_sizes[0] / (H * W);            // 8*64 = 512

    dim3 block(256, 1, 1);
    dim3 grid((OW + 255) / 256, OH, BC);
    hipLaunchKernelGGL(upfirdn_up2_k4, grid, block, 0, stream,
                       x, k, out, H, W, OH, OW);
}

// Round 2
// 216.119 us; speedup vs baseline: 1.8971x; 1.8971x over previous
//
#include <hip/hip_runtime.h>

// UpsampleUpFIRDn (up=2, k=4x4): each output pixel = 2x2 input taps with
// parity-selected weights. Input-centric: thread (ty, q) covers input rows
// ty-1..ty+1, cols 2q-1..2q+2 and produces outputs (2ty..2ty+1, 4q..4q+3).
//
// Weight map (kernel k[4][4], flipped conv == correlation handled in deriv):
//   out row even (oy=2ty):  tap row ty-1 -> k[3][*], tap row ty -> k[1][*]
//   out row odd  (oy=2ty+1): tap row ty  -> k[2][*], tap row ty+1 -> k[0][*]
//   out col even: tap cols (c-1,c) -> k[*][3], k[*][1]
//   out col odd:  tap cols (c,c+1) -> k[*][2], k[*][0]

__global__ __launch_bounds__(256) void up2_k4_2x4(
    const float* __restrict__ x, const float* __restrict__ kw,
    float* __restrict__ out)
{
    const int H = 256, W = 256, OH = 511, OW = 511;
    int q  = threadIdx.x;                               // 0..127 (col pair)
    int ty = blockIdx.y * blockDim.y + threadIdx.y;     // 0..255
    int bc = blockIdx.z;

    // Uniform pointer -> scalar loads into SGPRs (no vector-mem traffic).
    const float4* k4 = (const float4*)kw;
    float4 k0 = k4[0], k1 = k4[1], k2 = k4[2], k3 = k4[3];

    const float* __restrict__ xp = x + (size_t)bc * (H * W);
    int rm = (ty > 0)   ? ty - 1 : 0;        // clamped; zeroed below when ty==0
    int rp = (ty < H-1) ? ty + 1 : H - 1;    // only feeds odd row, unstored at ty=255
    int ca = (q > 0)    ? 2*q - 1 : 0;       // zeroed below when q==0
    int cb = 2*q, cc = 2*q + 1;
    int cd = (q < 127)  ? 2*q + 2 : W - 1;   // only feeds s3, unstored at q=127

    const float* prm = xp + (size_t)rm * W;
    const float* pr0 = xp + (size_t)ty * W;
    const float* prp = xp + (size_t)rp * W;

    float m_a = prm[ca], m_b = prm[cb], m_c = prm[cc], m_d = prm[cd];
    float z_a = pr0[ca], z_b = pr0[cb], z_c = pr0[cc], z_d = pr0[cd];
    float p_a = prp[ca], p_b = prp[cb], p_c = prp[cc], p_d = prp[cd];

    if (ty == 0) { m_a = 0.f; m_b = 0.f; m_c = 0.f; m_d = 0.f; }  // pad row
    if (q == 0)  { m_a = 0.f; z_a = 0.f; p_a = 0.f; }             // pad col

    // even out-row (oy = 2ty): rows -> k3 (top tap), k1 (bottom tap)
    float e0 = k3.w*m_a + k3.y*m_b + k1.w*z_a + k1.y*z_b;  // ox=4q   (even)
    float e1 = k3.z*m_b + k3.x*m_c + k1.z*z_b + k1.x*z_c;  // ox=4q+1 (odd)
    float e2 = k3.w*m_b + k3.y*m_c + k1.w*z_b + k1.y*z_c;  // ox=4q+2 (even)
    float e3 = k3.z*m_c + k3.x*m_d + k1.z*z_c + k1.x*z_d;  // ox=4q+3 (odd)
    // odd out-row (oy = 2ty+1): rows -> k2 (top tap), k0 (bottom tap)
    float o0 = k2.w*z_a + k2.y*z_b + k0.w*p_a + k0.y*p_b;
    float o1 = k2.z*z_b + k2.x*z_c + k0.z*p_b + k0.x*p_c;
    float o2 = k2.w*z_b + k2.y*z_c + k0.w*p_b + k0.y*p_c;
    float o3 = k2.z*z_c + k2.x*z_d + k0.z*p_c + k0.x*p_d;

    size_t ebase = ((size_t)bc * OH + (size_t)(2*ty)) * OW + 4*q;
    out[ebase + 0] = e0;
    out[ebase + 1] = e1;
    out[ebase + 2] = e2;
    if (q < 127) out[ebase + 3] = e3;
    if (ty < H - 1) {
        size_t obase = ebase + OW;
        out[obase + 0] = o0;
        out[obase + 1] = o1;
        out[obase + 2] = o2;
        if (q < 127) out[obase + 3] = o3;
    }
}

extern "C" void kernel_launch(void* const* d_in, const int* in_sizes, int n_in,
                              void* d_out, int out_size, void* d_ws, size_t ws_size,
                              hipStream_t stream) {
    const float* x = (const float*)d_in[0];
    const float* k = (const float*)d_in[1];
    float* out = (float*)d_out;

    const int H = 256, W = 256;
    int BC = in_sizes[0] / (H * W);  // 512

    dim3 block(128, 2, 1);           // q x ty-sub
    dim3 grid(1, H / 2, BC);         // (1, 128, 512)
    hipLaunchKernelGGL(up2_k4_2x4, grid, block, 0, stream, x, k, out);
}